// Round 7
// baseline (627.938 us; speedup 1.0000x reference)
//
#include <hip/hip_runtime.h>
#include <math.h>

#define N_NODES 40000
#define M_PAD   40064      // 313 * 128
#define N_EDGES 640000
#define D       256
#define H       8
#define DFF     1024
#define D3      768
#define ATT_SCALE 0.0625f  // 256^-0.5
#define LN_EPS  1e-5f

typedef __attribute__((ext_vector_type(8))) short short8;
typedef __attribute__((ext_vector_type(4))) float f32x4;

__device__ __forceinline__ unsigned short f2bf(float f) {
    unsigned int u = __builtin_bit_cast(unsigned int, f);
    u = (u + 0x7FFF + ((u >> 16) & 1)) >> 16;   // RTNE
    return (unsigned short)u;
}
__device__ __forceinline__ float bf2f(unsigned short u) {
    return __builtin_bit_cast(float, (unsigned int)u << 16);
}

// ---------------------------------------------------------------------------
// prep_kernel: grid-partitioned fusion of [hist | LN1 | pack Wqkv/W_in/W_out].
// All parts independent; one launch instead of five.
// ---------------------------------------------------------------------------
#define HIST_B  (N_EDGES / 256)          // 2500
#define LN_B    (N_NODES / 4)            // 10000
#define PQKV_B  ((D * D3 / 8) / 256)     // 96
#define PIN_B   ((D * DFF / 8) / 256)    // 128
#define POUT_B  ((DFF * D / 8) / 256)    // 128

__device__ __forceinline__ void ln_body(const float* __restrict__ in,
                                        const float* __restrict__ g,
                                        const float* __restrict__ b,
                                        unsigned short* __restrict__ out,
                                        int row, int lane)
{
    const float4 v = *reinterpret_cast<const float4*>(in + (size_t)row * D + lane * 4);
    float s  = v.x + v.y + v.z + v.w;
    float s2 = v.x * v.x + v.y * v.y + v.z * v.z + v.w * v.w;
#pragma unroll
    for (int o = 32; o > 0; o >>= 1) {
        s  += __shfl_xor(s,  o, 64);
        s2 += __shfl_xor(s2, o, 64);
    }
    const float mu  = s * (1.0f / D);
    const float var = s2 * (1.0f / D) - mu * mu;
    const float rs  = rsqrtf(var + LN_EPS);
    const float4 gg = *reinterpret_cast<const float4*>(g + lane * 4);
    const float4 bb = *reinterpret_cast<const float4*>(b + lane * 4);
    ushort4 o4;
    o4.x = f2bf((v.x - mu) * rs * gg.x + bb.x);
    o4.y = f2bf((v.y - mu) * rs * gg.y + bb.y);
    o4.z = f2bf((v.z - mu) * rs * gg.z + bb.z);
    o4.w = f2bf((v.w - mu) * rs * gg.w + bb.w);
    // fragment order: [row/16][D/8 chunks][16][8]; lane covers cols lane*4..+3
    const size_t off = (((size_t)(row >> 4) * (D / 8) + (lane >> 1)) * 16 + (row & 15)) * 8
                       + (lane & 1) * 4;
    *reinterpret_cast<ushort4*>(out + off) = o4;
}

__device__ __forceinline__ void pack_body(const float* __restrict__ W,
                                          unsigned short* __restrict__ Wpk,
                                          int idx, int K, int N)
{
    const int ni  = idx & 15;
    const int kc  = (idx >> 4) % (K / 8);
    const int nt  = idx / (16 * (K / 8));
    const int n   = nt * 16 + ni;
    unsigned short o[8];
#pragma unroll
    for (int i = 0; i < 8; ++i)
        o[i] = f2bf(W[(size_t)(kc * 8 + i) * N + n]);
    *reinterpret_cast<short8*>(Wpk + (size_t)idx * 8) = *reinterpret_cast<short8*>(o);
}

__global__ __launch_bounds__(256) void prep_kernel(const int* __restrict__ dst,
                                                   int* __restrict__ counts,
                                                   const float* __restrict__ triplet_h,
                                                   const float* __restrict__ ln_g,
                                                   const float* __restrict__ ln_b,
                                                   unsigned short* __restrict__ h,
                                                   const float* __restrict__ Wqkv,
                                                   unsigned short* __restrict__ Wqkv_pk,
                                                   const float* __restrict__ W_in,
                                                   unsigned short* __restrict__ Win_pk,
                                                   const float* __restrict__ W_out,
                                                   unsigned short* __restrict__ Wout_pk)
{
    const int b = blockIdx.x;
    if (b < HIST_B) {
        atomicAdd(&counts[dst[b * 256 + threadIdx.x]], 1);
    } else if (b < HIST_B + LN_B) {
        const int bb = b - HIST_B;
        ln_body(triplet_h, ln_g, ln_b, h,
                bb * 4 + (threadIdx.x >> 6), threadIdx.x & 63);
    } else if (b < HIST_B + LN_B + PQKV_B) {
        pack_body(Wqkv, Wqkv_pk, (b - HIST_B - LN_B) * 256 + threadIdx.x, D, D3);
    } else if (b < HIST_B + LN_B + PQKV_B + PIN_B) {
        pack_body(W_in, Win_pk, (b - HIST_B - LN_B - PQKV_B) * 256 + threadIdx.x, D, DFF);
    } else {
        pack_body(W_out, Wout_pk, (b - HIST_B - LN_B - PQKV_B - PIN_B) * 256 + threadIdx.x, DFF, D);
    }
}

// ---------------------------------------------------------------------------
// bf16 MFMA GEMM — LDS-FREE. Both operands pre-packed in per-lane fragment
// order ([T/16][K/8][16][8]); each lane global_load_dwordx4's its fragment
// directly to VGPRs (coalesced 1 KB/wave). Weights stay hot in L1/L2; A
// re-reads served by L2/L3. No __syncthreads, no LDS.
// Block 256 thr = 4 waves; 128x128 tile; BK=32.
// EPI 0: bf16 C row-major, scale cols<256 by ATT_SCALE (qkv)
// EPI 1: bf16 C in fragment order with exact gelu (a1)
// EPI 2: fp32 C row-major += Xadd (final residual)
// ---------------------------------------------------------------------------
template <int EPI, int K, int N>
__global__ __launch_bounds__(256) void mfma_gemm_kernel(const unsigned short* __restrict__ A,
                                                        const unsigned short* __restrict__ Bpk,
                                                        const float* __restrict__ bias,
                                                        void* __restrict__ Cout,
                                                        const float* __restrict__ Xadd)
{
    const int tid  = threadIdx.x;
    const int wave = tid >> 6;
    const int lane = tid & 63;
    const int row0 = blockIdx.y * 128;
    const int col0 = blockIdx.x * 128;
    const int wm   = (wave >> 1) * 64;
    const int wn   = (wave & 1) * 64;

    f32x4 acc[4][4] = {};

    const int lsub  = lane >> 4;        // k-chunk 0..3 within BK=32
    const int lelem = (lane & 15) * 8;  // element offset within chunk

    const unsigned short* Abase = A   + ((size_t)(row0 / 16 + wm / 16) * (K / 8) + lsub) * 128 + lelem;
    const unsigned short* Bbase = Bpk + ((size_t)(col0 / 16 + wn / 16) * (K / 8) + lsub) * 128 + lelem;

    for (int k0 = 0; k0 < K; k0 += 32) {
        const int kq = k0 >> 3;
        short8 af[4], bf[4];
#pragma unroll
        for (int i = 0; i < 4; ++i) {
            af[i] = *reinterpret_cast<const short8*>(Abase + ((size_t)i * (K / 8) + kq) * 128);
            bf[i] = *reinterpret_cast<const short8*>(Bbase + ((size_t)i * (K / 8) + kq) * 128);
        }
#pragma unroll
        for (int i = 0; i < 4; ++i)
#pragma unroll
            for (int j = 0; j < 4; ++j)
                acc[i][j] = __builtin_amdgcn_mfma_f32_16x16x32_bf16(af[i], bf[j], acc[i][j], 0, 0, 0);
    }

    // C/D layout: col=lane&15, row=(lane>>4)*4+t
#pragma unroll
    for (int j = 0; j < 4; ++j) {
        const int col = col0 + wn + j * 16 + (lane & 15);
        const float bz = bias[col];
#pragma unroll
        for (int i = 0; i < 4; ++i) {
#pragma unroll
            for (int t = 0; t < 4; ++t) {
                const int r = row0 + wm + i * 16 + (lane >> 4) * 4 + t;
                if (r < N_NODES) {
                    float o = acc[i][j][t] + bz;
                    if (EPI == 0) {
                        if (col < 256) o *= ATT_SCALE;
                        ((unsigned short*)Cout)[(size_t)r * N + col] = f2bf(o);
                    } else if (EPI == 1) {
                        o = 0.5f * o * (1.0f + erff(o * 0.70710678118654752f));
                        const size_t off = (((size_t)(r >> 4) * (N / 8) + (col >> 3)) * 16
                                            + (r & 15)) * 8 + (col & 7);
                        ((unsigned short*)Cout)[off] = f2bf(o);
                    } else {
                        o += Xadd[(size_t)r * N + col];
                        ((float*)Cout)[(size_t)r * N + col] = o;
                    }
                }
            }
        }
    }
}

// ---------------------------------------------------------------------------
// CSR: chunked single-block scan (writes rowptr AND cursor) -> fill
// ---------------------------------------------------------------------------
__global__ __launch_bounds__(256) void scan_kernel(const int* __restrict__ counts,
                                                   int* __restrict__ rowptr,
                                                   int* __restrict__ cursor)
{
    const int PER = (N_NODES + 255) / 256;     // 157
    const int tid = threadIdx.x;
    const int base = tid * PER;
    int s = 0;
    for (int i = 0; i < PER; ++i) {
        const int idx = base + i;
        if (idx < N_NODES) s += counts[idx];
    }
    __shared__ int sm[256];
    sm[tid] = s;
    __syncthreads();
    for (int off = 1; off < 256; off <<= 1) {
        int t = (tid >= off) ? sm[tid - off] : 0;
        __syncthreads();
        sm[tid] += t;
        __syncthreads();
    }
    const int incl = sm[tid];
    int run = incl - s;
    for (int i = 0; i < PER; ++i) {
        const int idx = base + i;
        if (idx < N_NODES) {
            rowptr[idx] = run;
            cursor[idx] = run;
            run += counts[idx];
        }
    }
    if (tid == 255) rowptr[N_NODES] = incl;
}

__global__ __launch_bounds__(256) void fill_kernel(const int* __restrict__ src,
                                                   const int* __restrict__ dst,
                                                   int* __restrict__ cursor,
                                                   int* __restrict__ srcs)
{
    const int e = blockIdx.x * 256 + threadIdx.x;
    const int pos = atomicAdd(&cursor[dst[e]], 1);
    if (pos >= 0 && pos < N_EDGES) srcs[pos] = src[e];
}

// ---------------------------------------------------------------------------
// Fused attention: score + single-pass softmax + aggregate + residual + LN2.
// One wave per dst node; 4-edge ILP unroll. qkv bf16 row-major, q pre-scaled.
// Outputs: x fp32 row-major, xn bf16 fragment order.
// ---------------------------------------------------------------------------
__global__ __launch_bounds__(256) void fused_attn_kernel(const unsigned short* __restrict__ qkv,
                                                         const int* __restrict__ srcs,
                                                         const int* __restrict__ rowptr,
                                                         const float* __restrict__ triplet_h,
                                                         const float* __restrict__ g,
                                                         const float* __restrict__ b,
                                                         float* __restrict__ x,
                                                         unsigned short* __restrict__ xn)
{
    const int node = blockIdx.x * 4 + (threadIdx.x >> 6);
    const int lane = threadIdx.x & 63;
    int beg = rowptr[node];
    int end = rowptr[node + 1];
    beg = max(0, min(beg, N_EDGES));
    end = max(beg, min(end, N_EDGES));

    const ushort4 ku = *reinterpret_cast<const ushort4*>(
        qkv + (size_t)node * D3 + 256 + lane * 4);
    const float k0 = bf2f(ku.x), k1 = bf2f(ku.y), k2 = bf2f(ku.z), k3 = bf2f(ku.w);

    float dsum = 0.0f;
    float4 acc = {0.0f, 0.0f, 0.0f, 0.0f};

    int j = beg;
    for (; j + 4 <= end; j += 4) {
        const int s0 = srcs[j], s1 = srcs[j + 1], s2 = srcs[j + 2], s3 = srcs[j + 3];
        const ushort4 qa = *reinterpret_cast<const ushort4*>(qkv + (size_t)s0 * D3 + lane * 4);
        const ushort4 qb = *reinterpret_cast<const ushort4*>(qkv + (size_t)s1 * D3 + lane * 4);
        const ushort4 qc = *reinterpret_cast<const ushort4*>(qkv + (size_t)s2 * D3 + lane * 4);
        const ushort4 qd = *reinterpret_cast<const ushort4*>(qkv + (size_t)s3 * D3 + lane * 4);
        const ushort4 va = *reinterpret_cast<const ushort4*>(qkv + (size_t)s0 * D3 + 512 + lane * 4);
        const ushort4 vb = *reinterpret_cast<const ushort4*>(qkv + (size_t)s1 * D3 + 512 + lane * 4);
        const ushort4 vc = *reinterpret_cast<const ushort4*>(qkv + (size_t)s2 * D3 + 512 + lane * 4);
        const ushort4 vd = *reinterpret_cast<const ushort4*>(qkv + (size_t)s3 * D3 + 512 + lane * 4);
        float pa = bf2f(qa.x) * k0 + bf2f(qa.y) * k1 + bf2f(qa.z) * k2 + bf2f(qa.w) * k3;
        float pb = bf2f(qb.x) * k0 + bf2f(qb.y) * k1 + bf2f(qb.z) * k2 + bf2f(qb.w) * k3;
        float pc = bf2f(qc.x) * k0 + bf2f(qc.y) * k1 + bf2f(qc.z) * k2 + bf2f(qc.w) * k3;
        float pd = bf2f(qd.x) * k0 + bf2f(qd.y) * k1 + bf2f(qd.z) * k2 + bf2f(qd.w) * k3;
        pa += __shfl_xor(pa, 1, 64);  pb += __shfl_xor(pb, 1, 64);
        pc += __shfl_xor(pc, 1, 64);  pd += __shfl_xor(pd, 1, 64);
        pa += __shfl_xor(pa, 2, 64);  pb += __shfl_xor(pb, 2, 64);
        pc += __shfl_xor(pc, 2, 64);  pd += __shfl_xor(pd, 2, 64);
        pa += __shfl_xor(pa, 4, 64);  pb += __shfl_xor(pb, 4, 64);
        pc += __shfl_xor(pc, 4, 64);  pd += __shfl_xor(pd, 4, 64);
        const float wa = __expf(pa), wb = __expf(pb), wc = __expf(pc), wd = __expf(pd);
        acc.x += wa * bf2f(va.x) + wb * bf2f(vb.x) + wc * bf2f(vc.x) + wd * bf2f(vd.x);
        acc.y += wa * bf2f(va.y) + wb * bf2f(vb.y) + wc * bf2f(vc.y) + wd * bf2f(vd.y);
        acc.z += wa * bf2f(va.z) + wb * bf2f(vb.z) + wc * bf2f(vc.z) + wd * bf2f(vd.z);
        acc.w += wa * bf2f(va.w) + wb * bf2f(vb.w) + wc * bf2f(vc.w) + wd * bf2f(vd.w);
        dsum += (wa + wb) + (wc + wd);
    }
    for (; j < end; ++j) {
        const int s0 = srcs[j];
        const ushort4 qa = *reinterpret_cast<const ushort4*>(qkv + (size_t)s0 * D3 + lane * 4);
        const ushort4 va = *reinterpret_cast<const ushort4*>(qkv + (size_t)s0 * D3 + 512 + lane * 4);
        float pa = bf2f(qa.x) * k0 + bf2f(qa.y) * k1 + bf2f(qa.z) * k2 + bf2f(qa.w) * k3;
        pa += __shfl_xor(pa, 1, 64);
        pa += __shfl_xor(pa, 2, 64);
        pa += __shfl_xor(pa, 4, 64);
        const float wa = __expf(pa);
        acc.x += wa * bf2f(va.x);
        acc.y += wa * bf2f(va.y);
        acc.z += wa * bf2f(va.z);
        acc.w += wa * bf2f(va.w);
        dsum += wa;
    }
    const float inv = (end > beg) ? 1.0f / dsum : 0.0f;

    const float4 th = *reinterpret_cast<const float4*>(
        triplet_h + (size_t)node * D + lane * 4);
    float4 xv;
    xv.x = th.x + acc.x * inv;
    xv.y = th.y + acc.y * inv;
    xv.z = th.z + acc.z * inv;
    xv.w = th.w + acc.w * inv;
    *reinterpret_cast<float4*>(x + (size_t)node * D + lane * 4) = xv;

    // LN2 across the wave
    float s  = xv.x + xv.y + xv.z + xv.w;
    float s2 = xv.x * xv.x + xv.y * xv.y + xv.z * xv.z + xv.w * xv.w;
#pragma unroll
    for (int o = 32; o > 0; o >>= 1) {
        s  += __shfl_xor(s,  o, 64);
        s2 += __shfl_xor(s2, o, 64);
    }
    const float mu  = s * (1.0f / D);
    const float var = s2 * (1.0f / D) - mu * mu;
    const float rs  = rsqrtf(var + LN_EPS);
    const float4 gg = *reinterpret_cast<const float4*>(g + lane * 4);
    const float4 bb = *reinterpret_cast<const float4*>(b + lane * 4);
    ushort4 o4;
    o4.x = f2bf((xv.x - mu) * rs * gg.x + bb.x);
    o4.y = f2bf((xv.y - mu) * rs * gg.y + bb.y);
    o4.z = f2bf((xv.z - mu) * rs * gg.z + bb.z);
    o4.w = f2bf((xv.w - mu) * rs * gg.w + bb.w);
    const size_t off = (((size_t)(node >> 4) * (D / 8) + (lane >> 1)) * 16 + (node & 15)) * 8
                       + (lane & 1) * 4;
    *reinterpret_cast<ushort4*>(xn + off) = o4;
}

// ---------------------------------------------------------------------------
extern "C" void kernel_launch(void* const* d_in, const int* in_sizes, int n_in,
                              void* d_out, int out_size, void* d_ws, size_t ws_size,
                              hipStream_t stream)
{
    const float* triplet_h = (const float*)d_in[0];
    const int*   src       = (const int*)d_in[1];
    const int*   dst       = (const int*)d_in[2];
    const float* Wqkv      = (const float*)d_in[3];
    const float* bqkv      = (const float*)d_in[4];
    const float* ln_attn_g = (const float*)d_in[5];
    const float* ln_attn_b = (const float*)d_in[6];
    const float* ln_res_g  = (const float*)d_in[7];
    const float* ln_res_b  = (const float*)d_in[8];
    const float* W_in      = (const float*)d_in[9];
    const float* b_in      = (const float*)d_in[10];
    const float* W_out     = (const float*)d_in[11];
    const float* b_out     = (const float*)d_in[12];
    float* out = (float*)d_out;

    // Workspace (~150 MB, under proven 245.76 MB ceiling):
    char* w = (char*)d_ws;
    unsigned short* bufA = (unsigned short*)w;   // qkv bf16 row-major OR a1 bf16 frag
    w += (size_t)M_PAD * DFF * sizeof(unsigned short);
    unsigned short* h_xn = (unsigned short*)w;  w += (size_t)M_PAD * D * sizeof(unsigned short);
    float*          x    = (float*)w;           w += (size_t)N_NODES * D * sizeof(float);
    unsigned short* Wqkv_pk = (unsigned short*)w; w += (size_t)D * D3 * sizeof(unsigned short);
    unsigned short* Win_pk  = (unsigned short*)w; w += (size_t)D * DFF * sizeof(unsigned short);
    unsigned short* Wout_pk = (unsigned short*)w; w += (size_t)DFF * D * sizeof(unsigned short);
    int* counts = (int*)w;  w += (size_t)N_NODES * sizeof(int);
    int* rowptr = (int*)w;  w += (size_t)(N_NODES + 1) * sizeof(int);
    int* cursor = (int*)w;  w += (size_t)N_NODES * sizeof(int);
    int* srcs   = (int*)w;  w += (size_t)N_EDGES * sizeof(int);

    unsigned short* qkv = bufA;  // [40000][768] bf16 row-major, dead after fused_attn
    unsigned short* a1  = bufA;  // fragment-order a1, live FFN only

    hipMemsetAsync(counts, 0, (size_t)N_NODES * sizeof(int), stream);
    // h/xn pad rows (rows 40000..40063) -> zero (frag region byte-identical)
    hipMemsetAsync(h_xn + (size_t)N_NODES * D, 0,
                   (size_t)(M_PAD - N_NODES) * D * sizeof(unsigned short), stream);

    // ---- fused prep: hist + LN1 + weight packs ----
    prep_kernel<<<HIST_B + LN_B + PQKV_B + PIN_B + POUT_B, 256, 0, stream>>>(
        dst, counts, triplet_h, ln_attn_g, ln_attn_b, h_xn,
        Wqkv, Wqkv_pk, W_in, Win_pk, W_out, Wout_pk);
    scan_kernel<<<1, 256, 0, stream>>>(counts, rowptr, cursor);
    fill_kernel<<<N_EDGES / 256, 256, 0, stream>>>(src, dst, cursor, srcs);

    // ---- main pipeline ----
    mfma_gemm_kernel<0, D, D3><<<dim3(D3 / 128, M_PAD / 128), 256, 0, stream>>>(
        h_xn, Wqkv_pk, bqkv, qkv, nullptr);
    fused_attn_kernel<<<N_NODES / 4, 256, 0, stream>>>(qkv, srcs, rowptr, triplet_h,
                                                       ln_res_g, ln_res_b, x, h_xn);
    // qkv dead; zero a1 pad region before FFN GEMMs
    hipMemsetAsync(a1 + (size_t)N_NODES * DFF, 0,
                   (size_t)(M_PAD - N_NODES) * DFF * sizeof(unsigned short), stream);
    mfma_gemm_kernel<1, D, DFF><<<dim3(DFF / 128, M_PAD / 128), 256, 0, stream>>>(
        h_xn, Win_pk, b_in, a1, nullptr);
    mfma_gemm_kernel<2, DFF, D><<<dim3(D / 128, M_PAD / 128), 256, 0, stream>>>(
        a1, Wout_pk, b_out, out, x);

    (void)in_sizes; (void)n_in; (void)out_size; (void)ws_size;
}

// Round 8
// 619.002 us; speedup vs baseline: 1.0144x; 1.0144x over previous
//
#include <hip/hip_runtime.h>
#include <math.h>

#define N_NODES 40000
#define M_PAD   40064      // 313 * 128
#define N_EDGES 640000
#define D       256
#define H       8
#define DFF     1024
#define D3      768
#define ATT_SCALE 0.0625f  // 256^-0.5
#define LN_EPS  1e-5f

typedef __attribute__((ext_vector_type(8))) short short8;
typedef __attribute__((ext_vector_type(4))) float f32x4;

__device__ __forceinline__ unsigned short f2bf(float f) {
    unsigned int u = __builtin_bit_cast(unsigned int, f);
    u = (u + 0x7FFF + ((u >> 16) & 1)) >> 16;   // RTNE
    return (unsigned short)u;
}
__device__ __forceinline__ float bf2f(unsigned short u) {
    return __builtin_bit_cast(float, (unsigned int)u << 16);
}

#define GLOAD_LDS16(g, l) \
    __builtin_amdgcn_global_load_lds((const __attribute__((address_space(1))) void*)(g), \
                                     (__attribute__((address_space(3))) void*)(l), 16, 0, 0)

// ---------------------------------------------------------------------------
// prep_kernel: grid-partitioned fusion of [hist | LN1 | pack Wqkv/W_in/W_out].
// ---------------------------------------------------------------------------
#define HIST_B  (N_EDGES / 256)          // 2500
#define LN_B    (N_NODES / 4)            // 10000
#define PQKV_B  ((D * D3 / 8) / 256)     // 96
#define PIN_B   ((D * DFF / 8) / 256)    // 128
#define POUT_B  ((DFF * D / 8) / 256)    // 128

__device__ __forceinline__ void ln_body(const float* __restrict__ in,
                                        const float* __restrict__ g,
                                        const float* __restrict__ b,
                                        unsigned short* __restrict__ out,
                                        int row, int lane)
{
    const float4 v = *reinterpret_cast<const float4*>(in + (size_t)row * D + lane * 4);
    float s  = v.x + v.y + v.z + v.w;
    float s2 = v.x * v.x + v.y * v.y + v.z * v.z + v.w * v.w;
#pragma unroll
    for (int o = 32; o > 0; o >>= 1) {
        s  += __shfl_xor(s,  o, 64);
        s2 += __shfl_xor(s2, o, 64);
    }
    const float mu  = s * (1.0f / D);
    const float var = s2 * (1.0f / D) - mu * mu;
    const float rs  = rsqrtf(var + LN_EPS);
    const float4 gg = *reinterpret_cast<const float4*>(g + lane * 4);
    const float4 bb = *reinterpret_cast<const float4*>(b + lane * 4);
    ushort4 o4;
    o4.x = f2bf((v.x - mu) * rs * gg.x + bb.x);
    o4.y = f2bf((v.y - mu) * rs * gg.y + bb.y);
    o4.z = f2bf((v.z - mu) * rs * gg.z + bb.z);
    o4.w = f2bf((v.w - mu) * rs * gg.w + bb.w);
    // fragment order: [row/16][D/8][16][8]; lane covers cols lane*4..+3
    const size_t off = (((size_t)(row >> 4) * (D / 8) + (lane >> 1)) * 16 + (row & 15)) * 8
                       + (lane & 1) * 4;
    *reinterpret_cast<ushort4*>(out + off) = o4;
}

__device__ __forceinline__ void pack_body(const float* __restrict__ W,
                                          unsigned short* __restrict__ Wpk,
                                          int idx, int K, int N)
{
    const int ni  = idx & 15;
    const int kc  = (idx >> 4) % (K / 8);
    const int nt  = idx / (16 * (K / 8));
    const int n   = nt * 16 + ni;
    unsigned short o[8];
#pragma unroll
    for (int i = 0; i < 8; ++i)
        o[i] = f2bf(W[(size_t)(kc * 8 + i) * N + n]);
    *reinterpret_cast<short8*>(Wpk + (size_t)idx * 8) = *reinterpret_cast<short8*>(o);
}

__global__ __launch_bounds__(256) void prep_kernel(const int* __restrict__ dst,
                                                   int* __restrict__ counts,
                                                   const float* __restrict__ triplet_h,
                                                   const float* __restrict__ ln_g,
                                                   const float* __restrict__ ln_b,
                                                   unsigned short* __restrict__ h,
                                                   const float* __restrict__ Wqkv,
                                                   unsigned short* __restrict__ Wqkv_pk,
                                                   const float* __restrict__ W_in,
                                                   unsigned short* __restrict__ Win_pk,
                                                   const float* __restrict__ W_out,
                                                   unsigned short* __restrict__ Wout_pk)
{
    const int b = blockIdx.x;
    if (b < HIST_B) {
        atomicAdd(&counts[dst[b * 256 + threadIdx.x]], 1);
    } else if (b < HIST_B + LN_B) {
        const int bb = b - HIST_B;
        ln_body(triplet_h, ln_g, ln_b, h,
                bb * 4 + (threadIdx.x >> 6), threadIdx.x & 63);
    } else if (b < HIST_B + LN_B + PQKV_B) {
        pack_body(Wqkv, Wqkv_pk, (b - HIST_B - LN_B) * 256 + threadIdx.x, D, D3);
    } else if (b < HIST_B + LN_B + PQKV_B + PIN_B) {
        pack_body(W_in, Win_pk, (b - HIST_B - LN_B - PQKV_B) * 256 + threadIdx.x, D, DFF);
    } else {
        pack_body(W_out, Wout_pk, (b - HIST_B - LN_B - PQKV_B - PIN_B) * 256 + threadIdx.x, DFF, D);
    }
}

// ---------------------------------------------------------------------------
// bf16 MFMA GEMM — hybrid staging.
// A (activations): block-shared via global_load_lds into 8 KB LDS (reused by
//   all 4 waves). B (weights, L2-resident): per-lane direct global->VGPR frag
//   loads, issued BEFORE the A barrier so they fly across it.
// A: [M/16][K/8][16][8]   B: [N/16][K/8][16][8]   128x128 tile, BK=32.
// EPI 0: bf16 C row-major, scale cols<256 by ATT_SCALE (qkv)
// EPI 1: bf16 C fragment-order with exact gelu (a1)
// EPI 2: fp32 C row-major += Xadd (final residual)
// ---------------------------------------------------------------------------
template <int EPI, int K, int N>
__global__ __launch_bounds__(256) void mfma_gemm_kernel(const unsigned short* __restrict__ A,
                                                        const unsigned short* __restrict__ Bpk,
                                                        const float* __restrict__ bias,
                                                        void* __restrict__ Cout,
                                                        const float* __restrict__ Xadd)
{
    __shared__ unsigned short As[4096];   // [mt8][kc4][mi16][ki8] = 8 KB

    const int tid  = threadIdx.x;
    const int wave = tid >> 6;
    const int lane = tid & 63;
    const int row0 = blockIdx.y * 128;
    const int col0 = blockIdx.x * 128;
    const int wm   = (wave >> 1) * 64;
    const int wn   = (wave & 1) * 64;

    f32x4 acc[4][4] = {};

    const int fragoff = (lane >> 4) * 128 + (lane & 15) * 8;
    const int lsub  = lane >> 4;
    const int lelem = (lane & 15) * 8;
    const unsigned short* Bbase =
        Bpk + ((size_t)(col0 / 16 + wn / 16) * (K / 8) + lsub) * 128 + lelem;

    for (int k0 = 0; k0 < K; k0 += 32) {
        const int kq = k0 >> 3;
        // B fragments: direct global loads (L2-hot), in flight across barrier
        short8 bf[4];
#pragma unroll
        for (int i = 0; i < 4; ++i)
            bf[i] = *reinterpret_cast<const short8*>(Bbase + ((size_t)i * (K / 8) + kq) * 128);
        // A tile: each wave DMAs 2 of 8 1-KB chunks
#pragma unroll
        for (int c = 0; c < 2; ++c) {
            const int mt = wave * 2 + c;
            GLOAD_LDS16(A + ((size_t)(row0 / 16 + mt) * (K / 8) + kq) * 128 + lane * 8,
                        &As[mt * 512]);
        }
        __syncthreads();

        short8 af[4];
#pragma unroll
        for (int i = 0; i < 4; ++i)
            af[i] = *reinterpret_cast<const short8*>(&As[(wm / 16 + i) * 512 + fragoff]);
#pragma unroll
        for (int i = 0; i < 4; ++i)
#pragma unroll
            for (int j = 0; j < 4; ++j)
                acc[i][j] = __builtin_amdgcn_mfma_f32_16x16x32_bf16(af[i], bf[j], acc[i][j], 0, 0, 0);
        __syncthreads();
    }

    // C/D layout: col=lane&15, row=(lane>>4)*4+t
#pragma unroll
    for (int j = 0; j < 4; ++j) {
        const int col = col0 + wn + j * 16 + (lane & 15);
        const float bz = bias[col];
#pragma unroll
        for (int i = 0; i < 4; ++i) {
#pragma unroll
            for (int t = 0; t < 4; ++t) {
                const int r = row0 + wm + i * 16 + (lane >> 4) * 4 + t;
                if (r < N_NODES) {
                    float o = acc[i][j][t] + bz;
                    if (EPI == 0) {
                        if (col < 256) o *= ATT_SCALE;
                        ((unsigned short*)Cout)[(size_t)r * N + col] = f2bf(o);
                    } else if (EPI == 1) {
                        o = 0.5f * o * (1.0f + erff(o * 0.70710678118654752f));
                        const size_t off = (((size_t)(r >> 4) * (N / 8) + (col >> 3)) * 16
                                            + (r & 15)) * 8 + (col & 7);
                        ((unsigned short*)Cout)[off] = f2bf(o);
                    } else {
                        o += Xadd[(size_t)r * N + col];
                        ((float*)Cout)[(size_t)r * N + col] = o;
                    }
                }
            }
        }
    }
}

// ---------------------------------------------------------------------------
// CSR: chunked single-block scan (writes rowptr AND cursor) -> fill
// ---------------------------------------------------------------------------
__global__ __launch_bounds__(256) void scan_kernel(const int* __restrict__ counts,
                                                   int* __restrict__ rowptr,
                                                   int* __restrict__ cursor)
{
    const int PER = (N_NODES + 255) / 256;     // 157
    const int tid = threadIdx.x;
    const int base = tid * PER;
    int s = 0;
    for (int i = 0; i < PER; ++i) {
        const int idx = base + i;
        if (idx < N_NODES) s += counts[idx];
    }
    __shared__ int sm[256];
    sm[tid] = s;
    __syncthreads();
    for (int off = 1; off < 256; off <<= 1) {
        int t = (tid >= off) ? sm[tid - off] : 0;
        __syncthreads();
        sm[tid] += t;
        __syncthreads();
    }
    const int incl = sm[tid];
    int run = incl - s;
    for (int i = 0; i < PER; ++i) {
        const int idx = base + i;
        if (idx < N_NODES) {
            rowptr[idx] = run;
            cursor[idx] = run;
            run += counts[idx];
        }
    }
    if (tid == 255) rowptr[N_NODES] = incl;
}

__global__ __launch_bounds__(256) void fill_kernel(const int* __restrict__ src,
                                                   const int* __restrict__ dst,
                                                   int* __restrict__ cursor,
                                                   int* __restrict__ srcs)
{
    const int e = blockIdx.x * 256 + threadIdx.x;
    const int pos = atomicAdd(&cursor[dst[e]], 1);
    if (pos >= 0 && pos < N_EDGES) srcs[pos] = src[e];
}

// ---------------------------------------------------------------------------
// Fused attention: score + single-pass softmax + aggregate + residual + LN2.
// One wave per dst node; 8-edge ILP unroll. qkv bf16 row-major, q pre-scaled.
// Outputs: x fp32 row-major, xn bf16 fragment order.
// ---------------------------------------------------------------------------
__global__ __launch_bounds__(256) void fused_attn_kernel(const unsigned short* __restrict__ qkv,
                                                         const int* __restrict__ srcs,
                                                         const int* __restrict__ rowptr,
                                                         const float* __restrict__ triplet_h,
                                                         const float* __restrict__ g,
                                                         const float* __restrict__ b,
                                                         float* __restrict__ x,
                                                         unsigned short* __restrict__ xn)
{
    const int node = blockIdx.x * 4 + (threadIdx.x >> 6);
    const int lane = threadIdx.x & 63;
    int beg = rowptr[node];
    int end = rowptr[node + 1];
    beg = max(0, min(beg, N_EDGES));
    end = max(beg, min(end, N_EDGES));

    const ushort4 ku = *reinterpret_cast<const ushort4*>(
        qkv + (size_t)node * D3 + 256 + lane * 4);
    const float k0 = bf2f(ku.x), k1 = bf2f(ku.y), k2 = bf2f(ku.z), k3 = bf2f(ku.w);

    float dsum = 0.0f;
    float4 acc = {0.0f, 0.0f, 0.0f, 0.0f};

    int j = beg;
    for (; j + 8 <= end; j += 8) {
        const unsigned short* rowp[8];
#pragma unroll
        for (int u = 0; u < 8; ++u)
            rowp[u] = qkv + (size_t)srcs[j + u] * D3 + lane * 4;
        ushort4 qs[8], vs[8];
#pragma unroll
        for (int u = 0; u < 8; ++u) {
            qs[u] = *reinterpret_cast<const ushort4*>(rowp[u]);
            vs[u] = *reinterpret_cast<const ushort4*>(rowp[u] + 512);
        }
        float p[8];
#pragma unroll
        for (int u = 0; u < 8; ++u)
            p[u] = bf2f(qs[u].x) * k0 + bf2f(qs[u].y) * k1
                 + bf2f(qs[u].z) * k2 + bf2f(qs[u].w) * k3;
#pragma unroll
        for (int u = 0; u < 8; ++u) p[u] += __shfl_xor(p[u], 1, 64);
#pragma unroll
        for (int u = 0; u < 8; ++u) p[u] += __shfl_xor(p[u], 2, 64);
#pragma unroll
        for (int u = 0; u < 8; ++u) p[u] += __shfl_xor(p[u], 4, 64);
#pragma unroll
        for (int u = 0; u < 8; ++u) {
            const float wgt = __expf(p[u]);
            acc.x += wgt * bf2f(vs[u].x);
            acc.y += wgt * bf2f(vs[u].y);
            acc.z += wgt * bf2f(vs[u].z);
            acc.w += wgt * bf2f(vs[u].w);
            dsum += wgt;
        }
    }
    for (; j < end; ++j) {
        const unsigned short* rp = qkv + (size_t)srcs[j] * D3 + lane * 4;
        const ushort4 qa = *reinterpret_cast<const ushort4*>(rp);
        const ushort4 va = *reinterpret_cast<const ushort4*>(rp + 512);
        float pa = bf2f(qa.x) * k0 + bf2f(qa.y) * k1 + bf2f(qa.z) * k2 + bf2f(qa.w) * k3;
        pa += __shfl_xor(pa, 1, 64);
        pa += __shfl_xor(pa, 2, 64);
        pa += __shfl_xor(pa, 4, 64);
        const float wgt = __expf(pa);
        acc.x += wgt * bf2f(va.x);
        acc.y += wgt * bf2f(va.y);
        acc.z += wgt * bf2f(va.z);
        acc.w += wgt * bf2f(va.w);
        dsum += wgt;
    }
    const float inv = (end > beg) ? 1.0f / dsum : 0.0f;

    const float4 th = *reinterpret_cast<const float4*>(
        triplet_h + (size_t)node * D + lane * 4);
    float4 xv;
    xv.x = th.x + acc.x * inv;
    xv.y = th.y + acc.y * inv;
    xv.z = th.z + acc.z * inv;
    xv.w = th.w + acc.w * inv;
    *reinterpret_cast<float4*>(x + (size_t)node * D + lane * 4) = xv;

    // LN2 across the wave
    float s  = xv.x + xv.y + xv.z + xv.w;
    float s2 = xv.x * xv.x + xv.y * xv.y + xv.z * xv.z + xv.w * xv.w;
#pragma unroll
    for (int o = 32; o > 0; o >>= 1) {
        s  += __shfl_xor(s,  o, 64);
        s2 += __shfl_xor(s2, o, 64);
    }
    const float mu  = s * (1.0f / D);
    const float var = s2 * (1.0f / D) - mu * mu;
    const float rs  = rsqrtf(var + LN_EPS);
    const float4 gg = *reinterpret_cast<const float4*>(g + lane * 4);
    const float4 bb = *reinterpret_cast<const float4*>(b + lane * 4);
    ushort4 o4;
    o4.x = f2bf((xv.x - mu) * rs * gg.x + bb.x);
    o4.y = f2bf((xv.y - mu) * rs * gg.y + bb.y);
    o4.z = f2bf((xv.z - mu) * rs * gg.z + bb.z);
    o4.w = f2bf((xv.w - mu) * rs * gg.w + bb.w);
    const size_t off = (((size_t)(node >> 4) * (D / 8) + (lane >> 1)) * 16 + (node & 15)) * 8
                       + (lane & 1) * 4;
    *reinterpret_cast<ushort4*>(xn + off) = o4;
}

// ---------------------------------------------------------------------------
extern "C" void kernel_launch(void* const* d_in, const int* in_sizes, int n_in,
                              void* d_out, int out_size, void* d_ws, size_t ws_size,
                              hipStream_t stream)
{
    const float* triplet_h = (const float*)d_in[0];
    const int*   src       = (const int*)d_in[1];
    const int*   dst       = (const int*)d_in[2];
    const float* Wqkv      = (const float*)d_in[3];
    const float* bqkv      = (const float*)d_in[4];
    const float* ln_attn_g = (const float*)d_in[5];
    const float* ln_attn_b = (const float*)d_in[6];
    const float* ln_res_g  = (const float*)d_in[7];
    const float* ln_res_b  = (const float*)d_in[8];
    const float* W_in      = (const float*)d_in[9];
    const float* b_in      = (const float*)d_in[10];
    const float* W_out     = (const float*)d_in[11];
    const float* b_out     = (const float*)d_in[12];
    float* out = (float*)d_out;

    // Workspace (~150 MB, under proven 245.76 MB ceiling):
    char* w = (char*)d_ws;
    unsigned short* bufA = (unsigned short*)w;   // qkv bf16 row-major OR a1 bf16 frag
    w += (size_t)M_PAD * DFF * sizeof(unsigned short);
    unsigned short* h_xn = (unsigned short*)w;  w += (size_t)M_PAD * D * sizeof(unsigned short);
    float*          x    = (float*)w;           w += (size_t)N_NODES * D * sizeof(float);
    unsigned short* Wqkv_pk = (unsigned short*)w; w += (size_t)D * D3 * sizeof(unsigned short);
    unsigned short* Win_pk  = (unsigned short*)w; w += (size_t)D * DFF * sizeof(unsigned short);
    unsigned short* Wout_pk = (unsigned short*)w; w += (size_t)DFF * D * sizeof(unsigned short);
    int* counts = (int*)w;  w += (size_t)N_NODES * sizeof(int);
    int* rowptr = (int*)w;  w += (size_t)(N_NODES + 1) * sizeof(int);
    int* cursor = (int*)w;  w += (size_t)N_NODES * sizeof(int);
    int* srcs   = (int*)w;  w += (size_t)N_EDGES * sizeof(int);

    unsigned short* qkv = bufA;  // row-major, dead after fused_attn
    unsigned short* a1  = bufA;  // fragment-order, live FFN only
    // Pad rows (40000..40063) of h_xn / a1 are never initialized: all GEMM
    // C-stores are guarded r < N_NODES, and attn reads nodes < N_NODES, so
    // garbage pad fragments only feed discarded accumulator rows.

    hipMemsetAsync(counts, 0, (size_t)N_NODES * sizeof(int), stream);

    // ---- fused prep: hist + LN1 + weight packs ----
    prep_kernel<<<HIST_B + LN_B + PQKV_B + PIN_B + POUT_B, 256, 0, stream>>>(
        dst, counts, triplet_h, ln_attn_g, ln_attn_b, h_xn,
        Wqkv, Wqkv_pk, W_in, Win_pk, W_out, Wout_pk);
    scan_kernel<<<1, 256, 0, stream>>>(counts, rowptr, cursor);
    fill_kernel<<<N_EDGES / 256, 256, 0, stream>>>(src, dst, cursor, srcs);

    // ---- main pipeline ----
    mfma_gemm_kernel<0, D, D3><<<dim3(D3 / 128, M_PAD / 128), 256, 0, stream>>>(
        h_xn, Wqkv_pk, bqkv, qkv, nullptr);
    fused_attn_kernel<<<N_NODES / 4, 256, 0, stream>>>(qkv, srcs, rowptr, triplet_h,
                                                       ln_res_g, ln_res_b, x, h_xn);
    mfma_gemm_kernel<1, D, DFF><<<dim3(DFF / 128, M_PAD / 128), 256, 0, stream>>>(
        h_xn, Win_pk, b_in, a1, nullptr);
    mfma_gemm_kernel<2, DFF, D><<<dim3(D / 128, M_PAD / 128), 256, 0, stream>>>(
        a1, Wout_pk, b_out, out, x);

    (void)in_sizes; (void)n_in; (void)out_size; (void)ws_size;
}